// Round 1
// baseline (655.004 us; speedup 1.0000x reference)
//
#include <hip/hip_runtime.h>
#include <cstdint>
#include <cstddef>

#define S_TOK 8192
#define MDIM  2048
#define NE    64
#define CAP   128

// d_out float layout: [0]=l_aux | [1..+67108864)=combine | [..+67108864)=dispatch | [..+64)=exp_counts
static const size_t COMBINE_OFF  = 1;
static const size_t DISPATCH_OFF = 1 + 67108864ULL;
static const size_t COUNTS_OFF   = 1 + 2ULL * 67108864ULL;
// Temporaries parked inside the combine region (consumed BEFORE the zero-fill kernel runs)
static const size_t WGT_OFF  = 1048576;   // 2048*64 floats
static const size_t PART_OFF = 2097152;   // 2*8192*64 floats (split-K partials)

// ---------------------------------------------------------------- transpose wg[e][k] -> wgT[k][e]
__global__ void k_transpose(const float* __restrict__ wg, float* __restrict__ wgT) {
    int tid = blockIdx.x * blockDim.x + threadIdx.x;   // 131072 total
    int k = tid >> 6, e = tid & 63;
    wgT[tid] = wg[(size_t)e * MDIM + k];
}

// ---------------------------------------------------------------- logits GEMM (fp32 VALU, split-K=2)
// grid (256 row-tiles, 2 k-halves), block 256. Tile: 32 rows x 64 experts, thread tile 2r x 4e.
#define RT 32
#define KC 32
__global__ __launch_bounds__(256) void k_gemm(const float* __restrict__ in,
                                              const float* __restrict__ wgT,
                                              float* __restrict__ part) {
    __shared__ float in_lds[KC][RT];   // [kk][r]
    __shared__ float wg_lds[KC][NE];   // [kk][e]
    int t  = threadIdx.x;
    int r0 = blockIdx.x * RT;
    int kbase = blockIdx.y * (MDIM / 2);
    int te = t & 15, tr = t >> 4;      // e0 = te*4, rows = {tr*2, tr*2+1}
    int lr = t & 31;                   // staging: row
    int lk = (t >> 5) << 2;            // staging: k group of 4
    float acc[2][4] = {{0.f,0.f,0.f,0.f},{0.f,0.f,0.f,0.f}};
    for (int kc = 0; kc < MDIM / 2; kc += KC) {
        int k0 = kbase + kc;
        float4 v = *(const float4*)(in + (size_t)(r0 + lr) * MDIM + k0 + lk);
        in_lds[lk + 0][lr] = v.x;
        in_lds[lk + 1][lr] = v.y;
        in_lds[lk + 2][lr] = v.z;
        in_lds[lk + 3][lr] = v.w;
        const float4* src = (const float4*)(wgT + (size_t)k0 * NE);   // contiguous 32x64 chunk
        float4* dst = (float4*)&wg_lds[0][0];
        dst[t]       = src[t];
        dst[t + 256] = src[t + 256];
        __syncthreads();
        #pragma unroll
        for (int kk = 0; kk < KC; ++kk) {
            float2 a = *(const float2*)&in_lds[kk][tr * 2];
            float4 b = *(const float4*)&wg_lds[kk][te * 4];
            acc[0][0] += a.x * b.x; acc[0][1] += a.x * b.y; acc[0][2] += a.x * b.z; acc[0][3] += a.x * b.w;
            acc[1][0] += a.y * b.x; acc[1][1] += a.y * b.y; acc[1][2] += a.y * b.z; acc[1][3] += a.y * b.w;
        }
        __syncthreads();
    }
    size_t base = ((size_t)blockIdx.y * S_TOK + r0 + tr * 2) * NE + te * 4;
    *(float4*)(part + base)      = make_float4(acc[0][0], acc[0][1], acc[0][2], acc[0][3]);
    *(float4*)(part + base + NE) = make_float4(acc[1][0], acc[1][1], acc[1][2], acc[1][3]);
}

// ---------------------------------------------------------------- softmax + argmax (lane = expert)
__global__ __launch_bounds__(256) void k_softmax(const float* __restrict__ part,
                                                 float* __restrict__ colsum,
                                                 float* __restrict__ gate_sel,
                                                 int* __restrict__ eid) {
    __shared__ float ls[NE];
    int t = threadIdx.x;
    int lane = t & 63, w = t >> 6;
    if (t < NE) ls[t] = 0.f;
    __syncthreads();
    float lsum = 0.f;
    for (int i = 0; i < 8; ++i) {
        int r = blockIdx.x * 32 + w * 8 + i;
        float v = part[(size_t)r * NE + lane] + part[(size_t)(S_TOK + r) * NE + lane];
        // max + first-index argmax across 64 lanes
        float m = v; int mi = lane;
        for (int off = 32; off > 0; off >>= 1) {
            float om = __shfl_xor(m, off);
            int   oi = __shfl_xor(mi, off);
            if (om > m || (om == m && oi < mi)) { m = om; mi = oi; }
        }
        float ex = expf(v - m);
        float s = ex;
        for (int off = 32; off > 0; off >>= 1) s += __shfl_xor(s, off);
        float gate = ex / s;
        lsum += gate;
        if (lane == mi) { gate_sel[r] = gate; eid[r] = mi; }
    }
    atomicAdd(&ls[lane], lsum);
    __syncthreads();
    if (t < NE) atomicAdd(&colsum[t], ls[t]);
}

// ---------------------------------------------------------------- zero-fill d_out (float4 grid-stride)
__global__ void k_zero(float4* __restrict__ p, long n4) {
    long i = (long)blockIdx.x * blockDim.x + threadIdx.x;
    long stride = (long)gridDim.x * blockDim.x;
    float4 z = make_float4(0.f, 0.f, 0.f, 0.f);
    for (; i < n4; i += stride) p[i] = z;
}

// ---------------------------------------------------------------- per-expert rank scan (+counts)
__global__ __launch_bounds__(256) void k_ranks(const int* __restrict__ eid,
                                               int* __restrict__ rank,
                                               float* __restrict__ counts,
                                               float* __restrict__ out_counts) {
    __shared__ int wsum[4];
    int e = blockIdx.x;
    int t = threadIdx.x;
    int lane = t & 63, w = t >> 6;
    int base = 0;
    for (int it = 0; it < S_TOK / 256; ++it) {
        int i = it * 256 + t;
        int m = (eid[i] == e) ? 1 : 0;
        unsigned long long b = __ballot(m);
        int pre = __popcll(b & ((1ull << lane) - 1ull));
        if (lane == 0) wsum[w] = __popcll(b);
        __syncthreads();
        int woff = 0;
        #pragma unroll
        for (int j = 0; j < 4; ++j) if (j < w) woff += wsum[j];
        int tot = wsum[0] + wsum[1] + wsum[2] + wsum[3];
        if (m) rank[i] = base + woff + pre;
        base += tot;
        __syncthreads();
    }
    if (t == 0) { counts[e] = (float)base; out_counts[e] = (float)base; }
}

// ---------------------------------------------------------------- l_aux = sum(me*ce)*E
__global__ void k_laux(const float* __restrict__ colsum, const float* __restrict__ counts,
                       float* __restrict__ out) {
    int t = threadIdx.x;   // 64 threads
    float x = (colsum[t] / 8192.f) * (counts[t] / 8192.f);
    for (int off = 32; off > 0; off >>= 1) x += __shfl_xor(x, off);
    if (t == 0) out[0] = x * 64.f;
}

// ---------------------------------------------------------------- scatter nonzeros
__global__ void k_scatter(const float* __restrict__ gate_sel, const int* __restrict__ eid,
                          const int* __restrict__ rank, float* __restrict__ out) {
    int s = blockIdx.x * blockDim.x + threadIdx.x;
    if (s >= S_TOK) return;
    int rk = rank[s];
    if (rk < CAP) {
        size_t idx = ((size_t)s * NE + eid[s]) * CAP + rk;
        out[COMBINE_OFF + idx]  = gate_sel[s];
        out[DISPATCH_OFF + idx] = 1.0f;
    }
}

extern "C" void kernel_launch(void* const* d_in, const int* in_sizes, int n_in,
                              void* d_out, int out_size, void* d_ws, size_t ws_size,
                              hipStream_t stream) {
    const float* in = (const float*)d_in[0];
    const float* wg = (const float*)d_in[1];
    float* out = (float*)d_out;
    float* wgT  = out + WGT_OFF;
    float* part = out + PART_OFF;

    float* colsum   = (float*)d_ws;            // 64 f
    float* gate_sel = colsum + 64;             // 8192 f
    int*   eid      = (int*)(gate_sel + 8192); // 8192 i
    int*   rank     = eid + 8192;              // 8192 i
    float* counts   = (float*)(rank + 8192);   // 64 f

    hipMemsetAsync(colsum, 0, 64 * sizeof(float), stream);
    k_transpose<<<512, 256, 0, stream>>>(wg, wgT);
    k_gemm<<<dim3(256, 2), 256, 0, stream>>>(in, wgT, part);
    k_softmax<<<256, 256, 0, stream>>>(part, colsum, gate_sel, eid);
    // zero-fill AFTER wgT/part consumed (they live in the combine region)
    k_zero<<<8192, 256, 0, stream>>>((float4*)out, 33554448L);   // covers [0, 134217792)
    k_ranks<<<64, 256, 0, stream>>>(eid, rank, counts, out + COUNTS_OFF);  // writes all counts incl. last elem
    k_laux<<<1, 64, 0, stream>>>(colsum, counts, out);
    k_scatter<<<32, 256, 0, stream>>>(gate_sel, eid, rank, out);
}

// Round 2
// 634.141 us; speedup vs baseline: 1.0329x; 1.0329x over previous
//
#include <hip/hip_runtime.h>
#include <cstdint>
#include <cstddef>

#define S_TOK 8192
#define MDIM  2048
#define NE    64
#define CAP   128

// d_out float layout: [0]=l_aux | [1..+67108864)=combine | [..+67108864)=dispatch | [..+64)=exp_counts
static const size_t COMBINE_OFF  = 1;
static const size_t DISPATCH_OFF = 1 + 67108864ULL;
static const size_t COUNTS_OFF   = 1 + 2ULL * 67108864ULL;
// Temporaries parked inside the combine region (consumed BEFORE the zero-fill kernel runs)
static const size_t WGT_OFF  = 1048576;   // 2048*64 floats
static const size_t PART_OFF = 2097152;   // 4*8192*64 floats (split-K partials)

// ---------------------------------------------------------------- transpose wg[e][k] -> wgT[k][e]
// LDS 64x64 tile, coalesced on both global sides; block 0 also zeroes colsum.
__global__ __launch_bounds__(256) void k_transpose(const float* __restrict__ wg,
                                                   float* __restrict__ wgT,
                                                   float* __restrict__ colsum) {
    __shared__ float tile[64][65];
    int t = threadIdx.x, b = blockIdx.x;          // b: k-tile 0..31
    if (b == 0 && t < 64) colsum[t] = 0.f;
    int kq = t & 15, eh = t >> 4;                 // load: 16 float4 along k, 16 e per phase
    #pragma unroll
    for (int p = 0; p < 4; ++p) {
        int e = p * 16 + eh;
        float4 v = *(const float4*)(wg + (size_t)e * MDIM + b * 64 + kq * 4);
        tile[e][kq * 4 + 0] = v.x;
        tile[e][kq * 4 + 1] = v.y;
        tile[e][kq * 4 + 2] = v.z;
        tile[e][kq * 4 + 3] = v.w;
    }
    __syncthreads();
    int eq = t & 15, kh = t >> 4;                 // store: 16 float4 along e, 16 k per phase
    #pragma unroll
    for (int p = 0; p < 4; ++p) {
        int k = p * 16 + kh;
        float4 w;
        w.x = tile[eq * 4 + 0][k];
        w.y = tile[eq * 4 + 1][k];
        w.z = tile[eq * 4 + 2][k];
        w.w = tile[eq * 4 + 3][k];
        *(float4*)(wgT + (size_t)(b * 64 + k) * NE + eq * 4) = w;
    }
}

// ---------------------------------------------------------------- logits GEMM (fp32 VALU, split-K=4)
// grid (128 row-tiles, 4 k-quarters), block 256. Tile: 64 rows x 64 experts, thread 4r x 4e.
#define RT 64
#define KC 32
__global__ __launch_bounds__(256) void k_gemm(const float* __restrict__ in,
                                              const float* __restrict__ wgT,
                                              float* __restrict__ part) {
    __shared__ float in_lds[KC][RT + 4];   // [kk][r], stride 68 keeps 16B align + 2-way-max banks
    __shared__ float wg_lds[KC][NE];       // [kk][e]
    int t  = threadIdx.x;
    int r0 = blockIdx.x * RT;
    int kbase = blockIdx.y * (MDIM / 4);
    int te = t & 15, tr = t >> 4;          // e0 = te*4, rows = tr*4..tr*4+3
    int lk4 = (t & 7) * 4;                 // staging: k group of 4 (8 lanes -> 128B contiguous)
    int lr  = t >> 3;                      // staging: row 0..31 (then +32)
    float acc[4][4] = {};
    for (int kc = 0; kc < MDIM / 4; kc += KC) {
        int k0 = kbase + kc;
        float4 v0 = *(const float4*)(in + (size_t)(r0 + lr) * MDIM + k0 + lk4);
        float4 v1 = *(const float4*)(in + (size_t)(r0 + lr + 32) * MDIM + k0 + lk4);
        in_lds[lk4 + 0][lr] = v0.x; in_lds[lk4 + 1][lr] = v0.y;
        in_lds[lk4 + 2][lr] = v0.z; in_lds[lk4 + 3][lr] = v0.w;
        in_lds[lk4 + 0][lr + 32] = v1.x; in_lds[lk4 + 1][lr + 32] = v1.y;
        in_lds[lk4 + 2][lr + 32] = v1.z; in_lds[lk4 + 3][lr + 32] = v1.w;
        const float4* src = (const float4*)(wgT + (size_t)k0 * NE);   // contiguous 32x64 chunk
        float4* dst = (float4*)&wg_lds[0][0];
        dst[t]       = src[t];
        dst[t + 256] = src[t + 256];
        __syncthreads();
        #pragma unroll
        for (int kk = 0; kk < KC; ++kk) {
            float4 a4 = *(const float4*)&in_lds[kk][tr * 4];
            float4 b4 = *(const float4*)&wg_lds[kk][te * 4];
            float a[4] = {a4.x, a4.y, a4.z, a4.w};
            float b[4] = {b4.x, b4.y, b4.z, b4.w};
            #pragma unroll
            for (int i = 0; i < 4; ++i)
                #pragma unroll
                for (int j = 0; j < 4; ++j)
                    acc[i][j] += a[i] * b[j];
        }
        __syncthreads();
    }
    #pragma unroll
    for (int i = 0; i < 4; ++i) {
        size_t base = ((size_t)blockIdx.y * S_TOK + r0 + tr * 4 + i) * NE + te * 4;
        *(float4*)(part + base) = make_float4(acc[i][0], acc[i][1], acc[i][2], acc[i][3]);
    }
}

// ---------------------------------------------------------------- softmax + argmax (lane = expert)
__global__ __launch_bounds__(256) void k_softmax(const float* __restrict__ part,
                                                 float* __restrict__ colsum,
                                                 float* __restrict__ gate_sel,
                                                 int* __restrict__ eid) {
    __shared__ float ls[NE];
    int t = threadIdx.x;
    int lane = t & 63, w = t >> 6;
    if (t < NE) ls[t] = 0.f;
    __syncthreads();
    float lsum = 0.f;
    for (int i = 0; i < 8; ++i) {
        int r = blockIdx.x * 32 + w * 8 + i;
        float v = part[(size_t)r * NE + lane]
                + part[(size_t)(S_TOK + r) * NE + lane]
                + part[(size_t)(2 * S_TOK + r) * NE + lane]
                + part[(size_t)(3 * S_TOK + r) * NE + lane];
        float m = v; int mi = lane;
        for (int off = 32; off > 0; off >>= 1) {
            float om = __shfl_xor(m, off);
            int   oi = __shfl_xor(mi, off);
            if (om > m || (om == m && oi < mi)) { m = om; mi = oi; }
        }
        float ex = expf(v - m);
        float s = ex;
        for (int off = 32; off > 0; off >>= 1) s += __shfl_xor(s, off);
        float gate = ex / s;
        lsum += gate;
        if (lane == mi) { gate_sel[r] = gate; eid[r] = mi; }
    }
    atomicAdd(&ls[lane], lsum);
    __syncthreads();
    if (t < NE) atomicAdd(&colsum[t], ls[t]);
}

// ---------------------------------------------------------------- zero-fill d_out (float4 grid-stride)
__global__ void k_zero(float4* __restrict__ p, long n4) {
    long i = (long)blockIdx.x * blockDim.x + threadIdx.x;
    long stride = (long)gridDim.x * blockDim.x;
    float4 z = make_float4(0.f, 0.f, 0.f, 0.f);
    for (; i < n4; i += stride) p[i] = z;
}

// ---------------------------------------------------------------- per-expert rank scan (+counts)
__global__ __launch_bounds__(256) void k_ranks(const int* __restrict__ eid,
                                               int* __restrict__ rank,
                                               float* __restrict__ counts,
                                               float* __restrict__ out_counts) {
    __shared__ int wsum[4];
    int e = blockIdx.x;
    int t = threadIdx.x;
    int lane = t & 63, w = t >> 6;
    int base = 0;
    for (int it = 0; it < S_TOK / 256; ++it) {
        int i = it * 256 + t;
        int m = (eid[i] == e) ? 1 : 0;
        unsigned long long b = __ballot(m);
        int pre = __popcll(b & ((1ull << lane) - 1ull));
        if (lane == 0) wsum[w] = __popcll(b);
        __syncthreads();
        int woff = 0;
        #pragma unroll
        for (int j = 0; j < 4; ++j) if (j < w) woff += wsum[j];
        int tot = wsum[0] + wsum[1] + wsum[2] + wsum[3];
        if (m) rank[i] = base + woff + pre;
        base += tot;
        __syncthreads();
    }
    if (t == 0) { counts[e] = (float)base; out_counts[e] = (float)base; }
}

// ---------------------------------------------------------------- scatter nonzeros + l_aux
__global__ void k_scatter(const float* __restrict__ gate_sel, const int* __restrict__ eid,
                          const int* __restrict__ rank, const float* __restrict__ colsum,
                          const float* __restrict__ counts, float* __restrict__ out) {
    int t = threadIdx.x;
    if (blockIdx.x == 0 && t < 64) {   // l_aux = sum(me*ce)*E, wave 0 only
        float x = (colsum[t] / 8192.f) * (counts[t] / 8192.f);
        for (int off = 32; off > 0; off >>= 1) x += __shfl_xor(x, off);
        if (t == 0) out[0] = x * 64.f;
    }
    int s = blockIdx.x * blockDim.x + t;
    if (s >= S_TOK) return;
    int rk = rank[s];
    if (rk < CAP) {
        size_t idx = ((size_t)s * NE + eid[s]) * CAP + rk;
        out[COMBINE_OFF + idx]  = gate_sel[s];
        out[DISPATCH_OFF + idx] = 1.0f;
    }
}

extern "C" void kernel_launch(void* const* d_in, const int* in_sizes, int n_in,
                              void* d_out, int out_size, void* d_ws, size_t ws_size,
                              hipStream_t stream) {
    const float* in = (const float*)d_in[0];
    const float* wg = (const float*)d_in[1];
    float* out = (float*)d_out;
    float* wgT  = out + WGT_OFF;
    float* part = out + PART_OFF;

    float* colsum   = (float*)d_ws;            // 64 f
    float* gate_sel = colsum + 64;             // 8192 f
    int*   eid      = (int*)(gate_sel + 8192); // 8192 i
    int*   rank     = eid + 8192;              // 8192 i
    float* counts   = (float*)(rank + 8192);   // 64 f

    k_transpose<<<32, 256, 0, stream>>>(wg, wgT, colsum);
    k_gemm<<<dim3(128, 4), 256, 0, stream>>>(in, wgT, part);
    k_softmax<<<256, 256, 0, stream>>>(part, colsum, gate_sel, eid);
    // zero-fill AFTER wgT/part consumed (they live in the combine region)
    k_zero<<<8192, 256, 0, stream>>>((float4*)out, 33554448L);   // covers [0, 134217792)
    k_ranks<<<64, 256, 0, stream>>>(eid, rank, counts, out + COUNTS_OFF);  // writes counts incl. last elem
    k_scatter<<<32, 256, 0, stream>>>(gate_sel, eid, rank, colsum, counts, out);
}

// Round 4
// 626.116 us; speedup vs baseline: 1.0461x; 1.0128x over previous
//
#include <hip/hip_runtime.h>
#include <cstdint>
#include <cstddef>

#define S_TOK 8192
#define MDIM  2048
#define NE    64
#define CAP   128

typedef float f32x4 __attribute__((ext_vector_type(4)));

// d_out float layout: [0]=l_aux | [1..+67108864)=combine | [..+67108864)=dispatch | [..+64)=exp_counts
static const size_t COMBINE_OFF  = 1;
static const size_t DISPATCH_OFF = 1 + 67108864ULL;
static const size_t COUNTS_OFF   = 1 + 2ULL * 67108864ULL;   // = 134217729

// ---------------------------------------------------------------- transpose wg[e][k] -> wgT[k][e]
// LDS 64x64 tile, coalesced on both global sides; block 0 also zeroes colsum.
__global__ __launch_bounds__(256) void k_transpose(const float* __restrict__ wg,
                                                   float* __restrict__ wgT,
                                                   float* __restrict__ colsum) {
    __shared__ float tile[64][65];
    int t = threadIdx.x, b = blockIdx.x;          // b: k-tile 0..31
    if (b == 0 && t < 64) colsum[t] = 0.f;
    int kq = t & 15, eh = t >> 4;
    #pragma unroll
    for (int p = 0; p < 4; ++p) {
        int e = p * 16 + eh;
        float4 v = *(const float4*)(wg + (size_t)e * MDIM + b * 64 + kq * 4);
        tile[e][kq * 4 + 0] = v.x;
        tile[e][kq * 4 + 1] = v.y;
        tile[e][kq * 4 + 2] = v.z;
        tile[e][kq * 4 + 3] = v.w;
    }
    __syncthreads();
    int eq = t & 15, kh = t >> 4;
    #pragma unroll
    for (int p = 0; p < 4; ++p) {
        int k = p * 16 + kh;
        float4 w;
        w.x = tile[eq * 4 + 0][k];
        w.y = tile[eq * 4 + 1][k];
        w.z = tile[eq * 4 + 2][k];
        w.w = tile[eq * 4 + 3][k];
        *(float4*)(wgT + (size_t)(b * 64 + k) * NE + eq * 4) = w;
    }
}

// ---------------------------------------------------------------- logits GEMM (split-K=4) + fused zero-fill
// grid (128 row-tiles, 4 k-quarters) = 512 blocks, block 256. Tile 64r x 64e, thread 4r x 4e.
// Each thread also writes 256+ float4 zeros to d_out (nontemporal), overlapping VALU compute.
#define RT 64
#define KC 32
__global__ __launch_bounds__(256) void k_gemm(const float* __restrict__ in,
                                              const float* __restrict__ wgT,
                                              float* __restrict__ part,
                                              f32x4* __restrict__ zout) {
    __shared__ float in_lds[KC][RT + 4];
    __shared__ float wg_lds[KC][NE];
    int t  = threadIdx.x;
    int r0 = blockIdx.x * RT;
    int kbase = blockIdx.y * (MDIM / 4);
    int bid = blockIdx.y * 128 + blockIdx.x;
    long gtid = (long)bid * 256 + t;               // 0..131071
    int te = t & 15, tr = t >> 4;
    int lk4 = (t & 7) * 4;
    int lr  = t >> 3;
    const f32x4 z4 = {0.f, 0.f, 0.f, 0.f};
    float acc[4][4] = {};
    for (int c = 0; c < 16; ++c) {
        int k0 = kbase + c * KC;
        float4 v0 = *(const float4*)(in + (size_t)(r0 + lr) * MDIM + k0 + lk4);
        float4 v1 = *(const float4*)(in + (size_t)(r0 + lr + 32) * MDIM + k0 + lk4);
        in_lds[lk4 + 0][lr] = v0.x; in_lds[lk4 + 1][lr] = v0.y;
        in_lds[lk4 + 2][lr] = v0.z; in_lds[lk4 + 3][lr] = v0.w;
        in_lds[lk4 + 0][lr + 32] = v1.x; in_lds[lk4 + 1][lr + 32] = v1.y;
        in_lds[lk4 + 2][lr + 32] = v1.z; in_lds[lk4 + 3][lr + 32] = v1.w;
        const float4* src = (const float4*)(wgT + (size_t)k0 * NE);
        float4* dst = (float4*)&wg_lds[0][0];
        dst[t]       = src[t];
        dst[t + 256] = src[t + 256];
        // fused zero-fill: 16 nontemporal float4 stores per chunk, grid-strided for coalescing
        #pragma unroll
        for (int j = 0; j < 16; ++j) {
            long idx = ((long)(c * 16 + j) << 17) + gtid;     // stride 131072 float4s
            __builtin_nontemporal_store(z4, zout + idx);
        }
        __syncthreads();
        #pragma unroll
        for (int kk = 0; kk < KC; ++kk) {
            float4 a4 = *(const float4*)&in_lds[kk][tr * 4];
            float4 b4 = *(const float4*)&wg_lds[kk][te * 4];
            float a[4] = {a4.x, a4.y, a4.z, a4.w};
            float b[4] = {b4.x, b4.y, b4.z, b4.w};
            #pragma unroll
            for (int i = 0; i < 4; ++i)
                #pragma unroll
                for (int j = 0; j < 4; ++j)
                    acc[i][j] += a[i] * b[j];
        }
        __syncthreads();
    }
    // tail: float4s [33554432, 33554448) -> covers floats up to 134217792
    if (gtid < 16) __builtin_nontemporal_store(z4, zout + 33554432 + gtid);
    #pragma unroll
    for (int i = 0; i < 4; ++i) {
        size_t base = ((size_t)blockIdx.y * S_TOK + r0 + tr * 4 + i) * NE + te * 4;
        *(float4*)(part + base) = make_float4(acc[i][0], acc[i][1], acc[i][2], acc[i][3]);
    }
}

// ---------------------------------------------------------------- softmax + argmax (lane = expert)
__global__ __launch_bounds__(256) void k_softmax(const float* __restrict__ part,
                                                 float* __restrict__ colsum,
                                                 float* __restrict__ gate_sel,
                                                 int* __restrict__ eid) {
    __shared__ float ls[NE];
    int t = threadIdx.x;
    int lane = t & 63, w = t >> 6;
    if (t < NE) ls[t] = 0.f;
    __syncthreads();
    float lsum = 0.f;
    for (int i = 0; i < 8; ++i) {
        int r = blockIdx.x * 32 + w * 8 + i;
        float v = part[(size_t)r * NE + lane]
                + part[(size_t)(S_TOK + r) * NE + lane]
                + part[(size_t)(2 * S_TOK + r) * NE + lane]
                + part[(size_t)(3 * S_TOK + r) * NE + lane];
        float m = v; int mi = lane;
        for (int off = 32; off > 0; off >>= 1) {
            float om = __shfl_xor(m, off);
            int   oi = __shfl_xor(mi, off);
            if (om > m || (om == m && oi < mi)) { m = om; mi = oi; }
        }
        float ex = expf(v - m);
        float s = ex;
        for (int off = 32; off > 0; off >>= 1) s += __shfl_xor(s, off);
        float gate = ex / s;
        lsum += gate;
        if (lane == mi) { gate_sel[r] = gate; eid[r] = mi; }
    }
    atomicAdd(&ls[lane], lsum);
    __syncthreads();
    if (t < NE) atomicAdd(&colsum[t], ls[t]);
}

// ---------------------------------------------------------------- ranks + scatter + counts + l_aux
// block e scans all tokens; rank = #earlier tokens routed to e; writes nonzeros inline.
__global__ __launch_bounds__(256) void k_ranks_scatter(const int* __restrict__ eid,
                                                       const float* __restrict__ gate_sel,
                                                       const float* __restrict__ colsum,
                                                       float* __restrict__ out) {
    __shared__ int wsum[4];
    int e = blockIdx.x;
    int t = threadIdx.x;
    int lane = t & 63, w = t >> 6;
    int base = 0;
    for (int it = 0; it < S_TOK / 256; ++it) {
        int s = it * 256 + t;
        int m = (eid[s] == e) ? 1 : 0;
        unsigned long long b = __ballot(m);
        int pre = __popcll(b & ((1ull << lane) - 1ull));
        if (lane == 0) wsum[w] = __popcll(b);
        __syncthreads();
        int woff = 0;
        #pragma unroll
        for (int j = 0; j < 4; ++j) if (j < w) woff += wsum[j];
        int tot = wsum[0] + wsum[1] + wsum[2] + wsum[3];
        if (m) {
            int rk = base + woff + pre;
            if (rk < CAP) {
                size_t idx = ((size_t)s * NE + e) * CAP + rk;
                out[COMBINE_OFF + idx]  = gate_sel[s];
                out[DISPATCH_OFF + idx] = 1.0f;
            }
        }
        base += tot;
        __syncthreads();
    }
    if (t == 0) {
        out[COUNTS_OFF + e] = (float)base;
        // l_aux contribution: (me_e) * (ce_e) * E  summed over e via atomics
        float term = (colsum[e] / 8192.f) * ((float)base / 8192.f) * 64.f;
        atomicAdd(out, term);
    }
}

extern "C" void kernel_launch(void* const* d_in, const int* in_sizes, int n_in,
                              void* d_out, int out_size, void* d_ws, size_t ws_size,
                              hipStream_t stream) {
    const float* in = (const float*)d_in[0];
    const float* wg = (const float*)d_in[1];
    float* out = (float*)d_out;

    float* colsum   = (float*)d_ws;              // 64 f
    float* gate_sel = colsum + 64;               // 8192 f
    int*   eid      = (int*)(gate_sel + 8192);   // 8192 i
    float* wgT      = (float*)(eid + 8192);      // 131072 f
    float* part     = wgT + 131072;              // 4*8192*64 f

    k_transpose<<<32, 256, 0, stream>>>(wg, wgT, colsum);
    k_gemm<<<dim3(128, 4), 256, 0, stream>>>(in, wgT, part, (f32x4*)out);   // also zeroes d_out
    k_softmax<<<256, 256, 0, stream>>>(part, colsum, gate_sel, eid);
    k_ranks_scatter<<<64, 256, 0, stream>>>(eid, gate_sel, colsum, out);    // counts + l_aux + nonzeros
}